// Round 15
// baseline (301.365 us; speedup 1.0000x reference)
//
#include <hip/hip_runtime.h>
#include <hip/hip_bf16.h>
#include <stdint.h>

// Problem constants
#define KK   8192
#define NN   16384      // B*H*W tokens
#define CCH  256        // channels

#define QE_SIZE  4194304            // NN*CCH floats
#define LOSS_OFF QE_SIZE
#define IDX_OFF  (QE_SIZE + 1)

// ws layout (bytes)
// SINGLE-PRODUCT GEMM: score = bf16(x)·bf16(e) - 0.5||e||^2 - 256.
// Codes in 8 EIGHTHS of 1024. GEMM v10 = r14 v9 gemm phase + DYNAMIC fused
// finalize: the 8th eighth-block to finish an mblk (last-block atomic
// pattern, device-scope fences) finalizes those 128 tokens in-kernel as
// 4 x 32-token tiles (r12-validated body). Finalize overlaps other blocks'
// GEMM; one launch boundary removed.
// hn[k] = -(0.5||e_k||^2 + 256); packed key =
// (~bits & 0xFFFFFC00) | (1023 - local_code); fp64 top-3 rescue recovers
// the exact argmin.
#define B2_OFF     0ULL                              // ushort B2[8192][256] (hi)
#define HN_OFF     (B2_OFF + 8192ULL*256*2)          // float hn[8192]
#define PK1_OFF    (HN_OFF + 8192ULL*4)              // uint pk1[8][16384]
#define PK2_OFF    (PK1_OFF + 8ULL*16384*4)          // uint pk2[8][16384]
#define CNT_OFF    (PK2_OFF + 8ULL*16384*4)          // int cnt[128]

typedef __attribute__((ext_vector_type(8))) short   bf16x8;
typedef __attribute__((ext_vector_type(8))) unsigned short ushort8v;
typedef __attribute__((ext_vector_type(4))) float   f32x4;

__device__ __forceinline__ void gld16(const void* g, void* l) {
    __builtin_amdgcn_global_load_lds(
        (const __attribute__((address_space(1))) void*)g,
        (__attribute__((address_space(3))) void*)l, 16, 0, 0);
}

// round-to-nearest-even fp32 -> bf16 bits
__device__ __forceinline__ unsigned short bf16_rn(float v) {
    uint32_t u = __float_as_uint(v);
    return (unsigned short)((u + 0x7fffu + ((u >> 16) & 1u)) >> 16);
}

// insert candidate (k, g) into running top-3 (key desc, idx asc on ties)
__device__ __forceinline__ void top3k_insert(unsigned& s1, int& i1,
                                             unsigned& s2, int& i2,
                                             unsigned& s3, int& i3,
                                             unsigned k, int g) {
    if (k > s1 || (k == s1 && g < i1)) {
        s3 = s2; i3 = i2; s2 = s1; i2 = i1; s1 = k; i1 = g;
    } else if (k > s2 || (k == s2 && g < i2)) {
        s3 = s2; i3 = i2; s2 = k; i2 = g;
    } else if (k > s3 || (k == s3 && g < i3)) {
        s3 = k; i3 = g;
    }
}

// ---------------------------------------------------------------------------
// Fused prep (one launch): blocks 0..255 = split_x tiles, 256..1279 = codebook.
// (Round-7 validated; block 256 also zeroes loss + cnt[128].)
// ---------------------------------------------------------------------------
__global__ __launch_bounds__(256) void prep_kernel(const float* __restrict__ x,
                                                   const float* __restrict__ cb,
                                                   unsigned short* __restrict__ A,
                                                   unsigned short* __restrict__ B2,
                                                   float* __restrict__ hn,
                                                   float* __restrict__ loss,
                                                   int* __restrict__ cnt) {
    __shared__ float xt[256 * 64];      // 64 KB, swizzled [c][tok] (x-path only)
    const int t = threadIdx.x;
    const int bid = blockIdx.x;

    if (bid >= 256) {
        const int cbid = bid - 256;
        if (cbid == 0) {
            if (t == 0) *loss = 0.f;
            if (t < 128) cnt[t] = 0;
        }
        const int code = cbid * 8 + (t >> 5);
        const int c8 = (t & 31) * 8;
        const float* cr = cb + (size_t)code * CCH + c8;
        float s = 0.f;
        unsigned short hi[8];
        #pragma unroll
        for (int u = 0; u < 8; ++u) {
            float v = cr[u];
            s += v * v;
            hi[u] = bf16_rn(v);
        }
        *(ushort8v*)(B2 + (size_t)code * 256 + c8) = *(ushort8v*)hi;
        #pragma unroll
        for (int off = 16; off; off >>= 1) s += __shfl_xor(s, off);
        if ((t & 31) == 0) hn[code] = -(0.5f * s + 256.0f);
        return;
    }

    const int n0 = bid * 64;
    const int b = n0 >> 10, hw0 = n0 & 1023;
    const int tok_l = t & 63, cg_ = t >> 6;
    const float* xb = x + ((size_t)b << 18) + hw0 + tok_l;
    #pragma unroll 8
    for (int i = 0; i < 64; ++i) {
        const int c = cg_ * 64 + i;
        xt[c * 64 + (tok_l ^ ((c >> 3) & 31))] = xb[(size_t)c << 10];
    }
    __syncthreads();
    const int tokq = t >> 5;            // 8 tokens per pass
    const int c8 = (t & 31) * 8;
    const int sw = (c8 >> 3) & 31;      // swizzle, uniform over u
    const int ksh = c8 >> 5;            // k-step
    const int lq  = (c8 >> 3) & 3;      // quad within frag
    for (int p = 0; p < 8; ++p) {
        int tk = p * 8 + tokq;
        const int tks = tk ^ sw;
        unsigned short hi[8];
        #pragma unroll
        for (int u = 0; u < 8; ++u)
            hi[u] = bf16_rn(xt[(c8 + u) * 64 + tks]);
        const int n  = n0 + tk;
        const int tb = n >> 4;
        const int l  = (tk & 15) + 16 * lq;
        *(ushort8v*)(A + ((size_t)((tb * 8 + ksh) * 64) + l) * 8) = *(ushort8v*)hi;
    }
}

// ---------------------------------------------------------------------------
// Main GEMM v10: r14 v9 gemm phase (M=32/wave, half-nt ping-pong staging,
// 3 blocks/CU) + last-block fused finalize.
// smem layout (40960 B):
//   gemm:     Bsm 2x2x8KB @0 (32KB), hn_sm 4KB @32768
//   finalize: xt 32KB @0, cnd[3][32] @32768, bsx[32] @33152,
//             dp[3][8][32] dbl @33280 (6KB, 8-aligned), amLast @40448
// ---------------------------------------------------------------------------
__global__ __launch_bounds__(256, 3) void vq_gemm_fin_kernel(
        const float* __restrict__ x, const float* __restrict__ cb,
        const unsigned short* __restrict__ A,
        const unsigned short* __restrict__ B2,
        const float* __restrict__ hn,
        unsigned* __restrict__ pk1, unsigned* __restrict__ pk2,
        int* __restrict__ cnt,
        float* __restrict__ qe, float* __restrict__ idx_f,
        float* __restrict__ loss) {
    __shared__ __align__(16) char smem[40960];

    const int t = threadIdx.x;
    const int lane = t & 63, wave = t >> 6;
    const int l15 = lane & 15, quad = lane >> 4;

    const int mblk = blockIdx.x & 127;        // 128 M-blocks of 128 tokens
    const int nq8  = blockIdx.x >> 7;         // 8 code eighths
    const int codeQ = nq8 * 1024;

    // ===================== GEMM phase (r14 v9, validated) =====================
    {
        unsigned short (*Bsm)[2][4096] = (unsigned short (*)[2][4096])smem;
        float* hn_sm = (float*)(smem + 32768);

        // A fragments: 16 coalesced dwordx4 loads, resident for the phase
        bf16x8 af[2][8];
        #pragma unroll
        for (int i = 0; i < 2; ++i) {
            const int tb = mblk * 8 + wave * 2 + i;   // 16-token tile id
            const unsigned short* Abase = A + ((size_t)(tb * 8) * 64 + lane) * 8;
            #pragma unroll
            for (int ks = 0; ks < 8; ++ks)
                af[i][ks] = *(const bf16x8*)(Abase + (size_t)ks * 64 * 8);
        }

        // hn eighth -> LDS (4 KB; one 1 KB wave-instr per wave)
        {
            const int boff = wave * 1024;
            gld16((const char*)(hn + codeQ) + boff + lane * 16,
                  (char*)hn_sm + boff);
        }

        const int srow = wave * 8 + (lane >> 3);          // + it*32
        const int sch  = (lane & 7) ^ (srow & 7);         // swizzled source chunk

#define STAGE_H(P, NT, H)                                                      \
    do {                                                                       \
        _Pragma("unroll")                                                      \
        for (int sp_ = 0; sp_ < 2; ++sp_) {                                    \
            char* dst = (char*)Bsm[P][sp_] + wave * 1024;                      \
            const size_t bOff = (size_t)(codeQ + (NT) * 64 + srow) * 256       \
                                + ((H) * 2 + sp_) * 64 + sch * 8;              \
            _Pragma("unroll")                                                  \
            for (int it = 0; it < 2; ++it)                                     \
                gld16(B2 + bOff + (size_t)it * (32 * 256), dst + it * 4096);   \
        }                                                                      \
    } while (0)

        unsigned K1[2][4], K2[2][4];
        #pragma unroll
        for (int i = 0; i < 2; ++i)
            #pragma unroll
            for (int r = 0; r < 4; ++r) { K1[i][r] = 0u; K2[i][r] = 0u; }

        STAGE_H(0, 0, 0);               // prologue prefetch (hn load in flight)
        __syncthreads();                // drains all prologue vmem, once

        int g = 0;                      // global stage counter (0..31)

        #pragma unroll 1
        for (int nt = 0; nt < 16; ++nt) {
            const int hb = nt * 64 + l15;
            f32x4 acc[2][4];
            #pragma unroll
            for (int j = 0; j < 4; ++j) {
                const float nh = hn_sm[hb + j * 16];
                #pragma unroll
                for (int i = 0; i < 2; ++i) {
                    f32x4 z = {nh, nh, nh, nh};
                    acc[i][j] = z;
                }
            }

            #pragma unroll
            for (int h = 0; h < 2; ++h) {
                if (g + 1 < 32) STAGE_H((g + 1) & 1, (g + 1) >> 1, (g + 1) & 1);

                #pragma unroll
                for (int sp = 0; sp < 2; ++sp) {
                    const char* bs = (const char*)Bsm[g & 1][sp];
                    #pragma unroll
                    for (int ks2 = 0; ks2 < 2; ++ks2) {
                        bf16x8 bfr[4];
                        #pragma unroll
                        for (int j = 0; j < 4; ++j) {
                            const int rowB = j * 16 + l15;
                            const int cbk = ((quad ^ (rowB & 7)) ^ (ks2 << 2)) * 16;
                            bfr[j] = *(const bf16x8*)(bs + rowB * 128 + cbk);
                        }
                        const int ka = h * 4 + sp * 2 + ks2;   // K-chunk 0..7
                        #pragma unroll
                        for (int i = 0; i < 2; ++i)
                            #pragma unroll
                            for (int j = 0; j < 4; ++j)
                                acc[i][j] = __builtin_amdgcn_mfma_f32_16x16x32_bf16(
                                    af[i][ka], bfr[j], acc[i][j], 0, 0, 0);
                    }
                }
                ++g;
                __syncthreads();   // stage g-1 consumed by all; stage g landed
            }

            // epilogue: branchless packed-key top-2 (all scores negative)
            const int icb = 1023 - (nt * 64 + l15);
            #pragma unroll
            for (int j = 0; j < 4; ++j) {
                const unsigned ic = (unsigned)(icb - j * 16);
                #pragma unroll
                for (int i = 0; i < 2; ++i)
                    #pragma unroll
                    for (int r = 0; r < 4; ++r) {
                        const unsigned u = __float_as_uint(acc[i][j][r]);
                        const unsigned k = (~u & 0xFFFFFC00u) | ic;
                        const unsigned lo = min(k, K1[i][r]);
                        K1[i][r] = max(k, K1[i][r]);
                        K2[i][r] = max(K2[i][r], lo);
                    }
            }
        }
#undef STAGE_H

        // top-2 butterfly across the 16-lane col groups (same tokens)
        #pragma unroll
        for (int off = 1; off < 16; off <<= 1) {
            #pragma unroll
            for (int i = 0; i < 2; ++i)
                #pragma unroll
                for (int r = 0; r < 4; ++r) {
                    const unsigned t1 = __shfl_xor(K1[i][r], off);
                    const unsigned t2 = __shfl_xor(K2[i][r], off);
                    const unsigned lo = min(K1[i][r], t1);
                    K1[i][r] = max(K1[i][r], t1);
                    K2[i][r] = max(max(K2[i][r], t2), lo);
                }
        }

        if (l15 == 0) {
            #pragma unroll
            for (int i = 0; i < 2; ++i)
                #pragma unroll
                for (int r = 0; r < 4; ++r) {
                    const int tok = mblk * 128 + wave * 32 + i * 16 + quad * 4 + r;
                    const int gi = nq8 * NN + tok;
                    pk1[gi] = K1[i][r]; pk2[gi] = K2[i][r];
                }
        }
    }

    // ============ last-block handoff (threadFenceReduction pattern) ============
    __threadfence();                       // release: my pk stores device-visible
    __syncthreads();                       // all threads' stores+fences done
    int* amLast = (int*)(smem + 40448);
    if (t == 0) {
        const int old = atomicAdd(&cnt[mblk], 1);
        *amLast = (old == 7);
    }
    __syncthreads();
    if (!*amLast) return;
    __threadfence();                       // acquire: see all 8 blocks' pk

    // ===================== fused finalize: 4 x 32-token tiles =====================
    // (r12-validated body, eighths-ported)
    float*  xt  = (float*)smem;                    // 32 KB swizzled [c][tok]
    int*    cnd = (int*)(smem + 32768);            // [3][32]
    int*    bsx = (int*)(smem + 33152);            // [32]
    double* dp  = (double*)(smem + 33280);         // [3][8][32] = 6 KB

    for (int tile = 0; tile < 4; ++tile) {
        const int n0 = mblk * 128 + tile * 32;
        const int b = n0 >> 10, hw0 = n0 & 1023;
        const int tok_l = t & 31, cg_ = t >> 5;    // cg_ in [0,8)

        // A: top-3 of the 16 per-eighth packed candidates (t<32)
        if (t < 32) {
            unsigned s1 = 0u, s2 = 0u, s3 = 0u;
            int i1 = 0x7ffffff, i2 = 0x7ffffff, i3 = 0x7ffffff;
            const int n = n0 + t;
            #pragma unroll
            for (int q = 0; q < 8; ++q) {
                const unsigned ka = pk1[q * NN + n];
                const unsigned kb = pk2[q * NN + n];
                const int ga = q * 1024 + 1023 - (int)(ka & 1023u);
                const int gb = q * 1024 + 1023 - (int)(kb & 1023u);
                top3k_insert(s1, i1, s2, i2, s3, i3, ka, ga);
                top3k_insert(s1, i1, s2, i2, s3, i3, kb, gb);
            }
            cnd[t] = i1; cnd[32 + t] = i2; cnd[64 + t] = i3;
        }

        // B: stage x transposed (coalesced along hw)
        const float* xb = x + ((size_t)b << 18) + hw0 + tok_l;
        #pragma unroll 8
        for (int i = 0; i < 32; ++i) {
            const int c = cg_ * 32 + i;
            xt[c * 32 + (tok_l ^ (c & 31))] = xb[(size_t)c << 10];
        }
        __syncthreads();

        // R: fp64 rescore of the 3 candidates; 8 threads per token
        {
            const int tok = t & 31, cq = t >> 5;
            const float* c0 = cb + (size_t)cnd[tok]      * CCH + cq * 32;
            const float* c1 = cb + (size_t)cnd[32 + tok] * CCH + cq * 32;
            const float* c2 = cb + (size_t)cnd[64 + tok] * CCH + cq * 32;
            double d0 = 0.0, d1 = 0.0, d2 = 0.0;
            #pragma unroll
            for (int j = 0; j < 32; j += 4) {
                const f32x4 e0 = *(const f32x4*)(c0 + j);
                const f32x4 e1 = *(const f32x4*)(c1 + j);
                const f32x4 e2 = *(const f32x4*)(c2 + j);
                #pragma unroll
                for (int u = 0; u < 4; ++u) {
                    const int c = cq * 32 + j + u;
                    const float xv = xt[c * 32 + (tok ^ (c & 31))];
                    const double dx0 = (double)xv - (double)e0[u];
                    const double dx1 = (double)xv - (double)e1[u];
                    const double dx2 = (double)xv - (double)e2[u];
                    d0 += dx0 * dx0;
                    d1 += dx1 * dx1;
                    d2 += dx2 * dx2;
                }
            }
            dp[(0 * 8 + cq) * 32 + tok] = d0;
            dp[(1 * 8 + cq) * 32 + tok] = d1;
            dp[(2 * 8 + cq) * 32 + tok] = d2;
        }
        __syncthreads();

        // P: pick true min of the 3 per token (t<32), idx, loss atomic
        if (t < 32) {
            double dd[3]; int ii[3];
            #pragma unroll
            for (int c = 0; c < 3; ++c) {
                double s = 0.0;
                #pragma unroll
                for (int q = 0; q < 8; ++q) s += dp[(c * 8 + q) * 32 + t];
                dd[c] = s;
                ii[c] = cnd[c * 32 + t];
            }
            int bi = ii[0]; double bd = dd[0];
            if (dd[1] < bd || (dd[1] == bd && ii[1] < bi)) { bd = dd[1]; bi = ii[1]; }
            if (dd[2] < bd || (dd[2] == bd && ii[2] < bi)) { bd = dd[2]; bi = ii[2]; }
            bsx[t] = bi;
            idx_f[n0 + t] = (float)bi;
            float lsum = (float)bd;
            #pragma unroll
            for (int off = 16; off; off >>= 1) lsum += __shfl_down(lsum, off);
            if (t == 0) atomicAdd(loss, lsum * (1.0f / ((float)NN * (float)CCH)));
        }
        __syncthreads();

        // C: load chosen code rows (row-contiguous, coalesced) into xt
        {
            const int w = t >> 6, lane_ = t & 63;     // 4 waves x 8 tokens
            #pragma unroll
            for (int i = 0; i < 8; ++i) {
                const int tok = w * 8 + i;
                const float* e = cb + (size_t)bsx[tok] * CCH;
                #pragma unroll
                for (int u = 0; u < 4; ++u) {
                    const int c = u * 64 + lane_;
                    xt[c * 32 + (tok ^ (c & 31))] = e[c];
                }
            }
        }
        __syncthreads();

        // D: write qe coalesced from the transposed LDS
        float* qb = qe + ((size_t)b << 18) + hw0 + tok_l;
        #pragma unroll 8
        for (int i = 0; i < 32; ++i) {
            const int c = cg_ * 32 + i;
            qb[(size_t)c << 10] = xt[c * 32 + (tok_l ^ (c & 31))];
        }
        __syncthreads();   // xt reused by next tile
    }
}

// ---------------------------------------------------------------------------
extern "C" void kernel_launch(void* const* d_in, const int* in_sizes, int n_in,
                              void* d_out, int out_size, void* d_ws, size_t ws_size,
                              hipStream_t stream) {
    const float* x  = (const float*)d_in[0];
    const float* cb = (const float*)d_in[1];
    float* out = (float*)d_out;
    char* ws = (char*)d_ws;

    // A (frag-major bf16) lives in d_out's qe region; finalize rewrites qe.
    unsigned short* A  = (unsigned short*)out;
    unsigned short* B2 = (unsigned short*)(ws + B2_OFF);
    float* hn  = (float*)(ws + HN_OFF);
    unsigned* pk1 = (unsigned*)(ws + PK1_OFF);
    unsigned* pk2 = (unsigned*)(ws + PK2_OFF);
    int* cnt = (int*)(ws + CNT_OFF);

    prep_kernel<<<256 + KK / 8, 256, 0, stream>>>(x, cb, A, B2, hn,
                                                  out + LOSS_OFF, cnt);
    vq_gemm_fin_kernel<<<1024, 256, 0, stream>>>(x, cb, A, B2, hn, pk1, pk2,
                                                 cnt, out, out + IDX_OFF,
                                                 out + LOSS_OFF);
}

// Round 16
// 164.676 us; speedup vs baseline: 1.8300x; 1.8300x over previous
//
#include <hip/hip_runtime.h>
#include <hip/hip_bf16.h>
#include <stdint.h>

// Problem constants
#define KK   8192
#define NN   16384      // B*H*W tokens
#define CCH  256        // channels

#define QE_SIZE  4194304            // NN*CCH floats
#define LOSS_OFF QE_SIZE
#define IDX_OFF  (QE_SIZE + 1)

// ws layout (bytes)
// SINGLE-PRODUCT GEMM: score = bf16(x)·bf16(e) - 0.5||e||^2 - 256.
// Quantization error sigma ~0.025 + 0.06 key truncation vs top-rank gaps
// ~3.8: the fp64 top-3 rescue in finalize recovers the exact argmin.
// hn[k] = -(0.5*||e_k||^2 + 256): acc-init. Bias keeps every score negative,
// so packed key = (~bits & 0xFFFFF800) | (2047 - local_code).
#define B2_OFF     0ULL                              // ushort B2[8192][256] (hi)
#define HN_OFF     (B2_OFF + 8192ULL*256*2)          // float hn[8192]
#define PK1_OFF    (HN_OFF + 8192ULL*4)              // uint pk1[4][16384]
#define PK2_OFF    (PK1_OFF + 4ULL*16384*4)          // uint pk2[4][16384]

typedef __attribute__((ext_vector_type(8))) short   bf16x8;
typedef __attribute__((ext_vector_type(8))) unsigned short ushort8v;
typedef __attribute__((ext_vector_type(4))) float   f32x4;

__device__ __forceinline__ void gld16(const void* g, void* l) {
    __builtin_amdgcn_global_load_lds(
        (const __attribute__((address_space(1))) void*)g,
        (__attribute__((address_space(3))) void*)l, 16, 0, 0);
}

// round-to-nearest-even fp32 -> bf16 bits
__device__ __forceinline__ unsigned short bf16_rn(float v) {
    uint32_t u = __float_as_uint(v);
    return (unsigned short)((u + 0x7fffu + ((u >> 16) & 1u)) >> 16);
}

// insert candidate (k, g) into running top-3 (key desc, idx asc on ties)
__device__ __forceinline__ void top3k_insert(unsigned& s1, int& i1,
                                             unsigned& s2, int& i2,
                                             unsigned& s3, int& i3,
                                             unsigned k, int g) {
    if (k > s1 || (k == s1 && g < i1)) {
        s3 = s2; i3 = i2; s2 = s1; i2 = i1; s1 = k; i1 = g;
    } else if (k > s2 || (k == s2 && g < i2)) {
        s3 = s2; i3 = i2; s2 = k; i2 = g;
    } else if (k > s3 || (k == s3 && g < i3)) {
        s3 = k; i3 = g;
    }
}

// ---------------------------------------------------------------------------
// Fused prep (one launch): blocks 0..255 = split_x tiles, 256..1279 = codebook.
// split_x: x -> A-FRAGMENT-MAJOR bf16 (hi only) in d_out's qe region.
// codebook: cb[8192][256] -> B2[k][256] hi-only bf16 + hn. Block 256
// thread 0 zeroes the loss accumulator.
// ---------------------------------------------------------------------------
__global__ __launch_bounds__(256) void prep_kernel(const float* __restrict__ x,
                                                   const float* __restrict__ cb,
                                                   unsigned short* __restrict__ A,
                                                   unsigned short* __restrict__ B2,
                                                   float* __restrict__ hn,
                                                   float* __restrict__ loss) {
    __shared__ float xt[256 * 64];      // 64 KB, swizzled [c][tok] (x-path only)
    const int t = threadIdx.x;
    const int bid = blockIdx.x;

    if (bid >= 256) {
        // ---- codebook path (no barriers) ----
        const int cbid = bid - 256;
        if (cbid == 0 && t == 0) *loss = 0.f;
        const int code = cbid * 8 + (t >> 5);
        const int c8 = (t & 31) * 8;
        const float* cr = cb + (size_t)code * CCH + c8;
        float s = 0.f;
        unsigned short hi[8];
        #pragma unroll
        for (int u = 0; u < 8; ++u) {
            float v = cr[u];
            s += v * v;
            hi[u] = bf16_rn(v);
        }
        *(ushort8v*)(B2 + (size_t)code * 256 + c8) = *(ushort8v*)hi;
        #pragma unroll
        for (int off = 16; off; off >>= 1) s += __shfl_xor(s, off);
        if ((t & 31) == 0) hn[code] = -(0.5f * s + 256.0f);
        return;
    }

    // ---- x path ----
    const int n0 = bid * 64;
    const int b = n0 >> 10, hw0 = n0 & 1023;
    const int tok_l = t & 63, cg = t >> 6;
    const float* xb = x + ((size_t)b << 18) + hw0 + tok_l;
    #pragma unroll 8
    for (int i = 0; i < 64; ++i) {
        const int c = cg * 64 + i;
        xt[c * 64 + (tok_l ^ ((c >> 3) & 31))] = xb[(size_t)c << 10];
    }
    __syncthreads();
    const int tokq = t >> 5;            // 8 tokens per pass
    const int c8 = (t & 31) * 8;
    const int sw = (c8 >> 3) & 31;      // swizzle, uniform over u
    const int ksh = c8 >> 5;            // k-step
    const int lq  = (c8 >> 3) & 3;      // quad within frag
    for (int p = 0; p < 8; ++p) {
        int tk = p * 8 + tokq;
        const int tks = tk ^ sw;
        unsigned short hi[8];
        #pragma unroll
        for (int u = 0; u < 8; ++u)
            hi[u] = bf16_rn(xt[(c8 + u) * 64 + tks]);
        const int n  = n0 + tk;
        const int tb = n >> 4;
        const int l  = (tk & 15) + 16 * lq;
        *(ushort8v*)(A + ((size_t)((tb * 8 + ksh) * 64) + l) * 8) = *(ushort8v*)hi;
    }
}

// ---------------------------------------------------------------------------
// Main: bf16 MFMA GEMM, fused branchless TOP-2 of (x·e - 0.5||e||^2 - 256).
// Best-measured configuration (165.5 µs total, gemm 76-78 µs, MfmaUtil ~37):
// single product (bf16 x · bf16 e); stage = FULL 64-code N-tile (32 KB =
// 4 slabs), 2x32 KB ping-pong, ONE barrier per nt; LDS ping-pong staging is
// the latency-hiding mechanism (L2-direct variant stalled: 135 µs).
// Epilogue: packed key = (~bits & 0xFFFFF800) | inv_code, 5 VALU per eval.
// ---------------------------------------------------------------------------
__global__ __launch_bounds__(256, 2) void vq_gemm_kernel(const unsigned short* __restrict__ A,
                                                         const unsigned short* __restrict__ B2,
                                                         const float* __restrict__ hn,
                                                         unsigned* __restrict__ pk1,
                                                         unsigned* __restrict__ pk2) {
    __shared__ unsigned short Bsm[2][4][4096];    // 2 x (4 slabs x 8 KB) ping-pong
    __shared__ float hn_sm[2048];                 // 8 KB, this quarter's acc-init

    const int t = threadIdx.x;
    const int lane = t & 63, wave = t >> 6;
    const int l15 = lane & 15, quad = lane >> 4;

    const int mblk = blockIdx.x & 127;        // 128 M-blocks of 128 tokens
    const int nq   = blockIdx.x >> 7;         // 4 code quarters
    const int codeQ = nq * 2048;

    // A fragments: 16 coalesced dwordx4 loads, resident for the whole kernel
    bf16x8 af[2][8];
    #pragma unroll
    for (int i = 0; i < 2; ++i) {
        const int tb = mblk * 8 + wave * 2 + i;   // 16-token tile id
        const unsigned short* Abase = A + ((size_t)(tb * 8) * 64 + lane) * 8;
        #pragma unroll
        for (int ks = 0; ks < 8; ++ks)
            af[i][ks] = *(const bf16x8*)(Abase + (size_t)ks * 64 * 8);
    }

    // hn quarter -> LDS (8 KB; 2 x 1 KB wave-instrs per wave)
    #pragma unroll
    for (int i = 0; i < 2; ++i) {
        const int boff = (wave * 2 + i) * 1024;               // wave-uniform LDS base
        gld16((const char*)(hn + codeQ) + boff + lane * 16,   // per-lane global
              (char*)hn_sm + boff);
    }

    // B staging geometry (global_load_lds: wave-uniform base + lane*16)
    const int srow = wave * 8 + (lane >> 3);          // + it*32
    const int sch  = (lane & 7) ^ (srow & 7);         // swizzled source chunk

    // stage a FULL nt (64 codes x 256 ch = 4 slabs x 8 KB) into buffer P
#define STAGE_NT(P, NT)                                                        \
    do {                                                                       \
        _Pragma("unroll")                                                      \
        for (int s_ = 0; s_ < 4; ++s_) {                                       \
            char* dst = (char*)Bsm[P][s_] + wave * 1024;                       \
            const size_t bOff = (size_t)(codeQ + (NT) * 64 + srow) * 256       \
                                + s_ * 64 + sch * 8;                           \
            _Pragma("unroll")                                                  \
            for (int it = 0; it < 2; ++it)                                     \
                gld16(B2 + bOff + (size_t)it * (32 * 256), dst + it * 4096);   \
        }                                                                      \
    } while (0)

    unsigned K1[2][4], K2[2][4];
    #pragma unroll
    for (int i = 0; i < 2; ++i)
        #pragma unroll
        for (int r = 0; r < 4; ++r) { K1[i][r] = 0u; K2[i][r] = 0u; }

    STAGE_NT(0, 0);                 // prologue prefetch (with hn loads in flight)
    __syncthreads();                // drains all prologue vmem, once

    #pragma unroll 1
    for (int nt = 0; nt < 32; ++nt) {
        // prefetch nt+1 into the other buffer; flies under this nt's compute
        if (nt + 1 < 32) STAGE_NT((nt + 1) & 1, nt + 1);

        // acc init = hn = -(0.5||e||^2 + 256): MFMA output IS the biased score
        const int hb = nt * 64 + l15;
        f32x4 acc[2][4];
        #pragma unroll
        for (int j = 0; j < 4; ++j) {
            const float nh = hn_sm[hb + j * 16];
            #pragma unroll
            for (int i = 0; i < 2; ++i) {
                f32x4 z = {nh, nh, nh, nh};
                acc[i][j] = z;
            }
        }

        #pragma unroll
        for (int st = 0; st < 4; ++st) {
            const char* bs = (const char*)Bsm[nt & 1][st];
            #pragma unroll
            for (int ks2 = 0; ks2 < 2; ++ks2) {
                bf16x8 bfr[4];
                #pragma unroll
                for (int j = 0; j < 4; ++j) {
                    const int rowB = j * 16 + l15;
                    const int cbk = ((quad ^ (rowB & 7)) ^ (ks2 << 2)) * 16;
                    bfr[j] = *(const bf16x8*)(bs + rowB * 128 + cbk);
                }
                const int ka = st * 2 + ks2;           // K-chunk 0..7
                #pragma unroll
                for (int i = 0; i < 2; ++i)
                    #pragma unroll
                    for (int j = 0; j < 4; ++j)        // x·e (single product)
                        acc[i][j] = __builtin_amdgcn_mfma_f32_16x16x32_bf16(
                            af[i][ka], bfr[j], acc[i][j], 0, 0, 0);
            }
        }

        // epilogue: branchless packed-key top-2 (all scores negative)
        const int icb = 2047 - (nt * 64 + l15);
        #pragma unroll
        for (int j = 0; j < 4; ++j) {
            const unsigned ic = (unsigned)(icb - j * 16);
            #pragma unroll
            for (int i = 0; i < 2; ++i)
                #pragma unroll
                for (int r = 0; r < 4; ++r) {
                    const unsigned u = __float_as_uint(acc[i][j][r]);
                    const unsigned k = (~u & 0xFFFFF800u) | ic;
                    const unsigned lo = min(k, K1[i][r]);
                    K1[i][r] = max(k, K1[i][r]);
                    K2[i][r] = max(K2[i][r], lo);
                }
        }

        __syncthreads();   // all waves done reading buf[nt&1]; nt+1 staged
    }
#undef STAGE_NT

    // top-2 butterfly across the 16-lane col groups (same tokens)
    #pragma unroll
    for (int off = 1; off < 16; off <<= 1) {
        #pragma unroll
        for (int i = 0; i < 2; ++i)
            #pragma unroll
            for (int r = 0; r < 4; ++r) {
                const unsigned t1 = __shfl_xor(K1[i][r], off);
                const unsigned t2 = __shfl_xor(K2[i][r], off);
                const unsigned lo = min(K1[i][r], t1);
                K1[i][r] = max(K1[i][r], t1);
                K2[i][r] = max(max(K2[i][r], t2), lo);
            }
    }

    // l15==0 lanes hold finals for tokens mblk*128 + wave*32 + i*16 + quad*4 + r
    if (l15 == 0) {
        #pragma unroll
        for (int i = 0; i < 2; ++i)
            #pragma unroll
            for (int r = 0; r < 4; ++r) {
                const int tok = mblk * 128 + wave * 32 + i * 16 + quad * 4 + r;
                const int gi = nq * NN + tok;
                pk1[gi] = K1[i][r]; pk2[gi] = K2[i][r];
            }
    }
}

// ---------------------------------------------------------------------------
// Finalize v5: 512 threads/block.
//   A) merge 8 per-quarter packed keys -> top-3 candidates (t<64)
//   B) stage x transposed, 8 channel-groups of 32 (coalesced)
//   R) fp64 rescore of 3 candidates, 8 threads/token (32 ch each)
//   P) pick true min of 3 (t<64), idx write, one loss atomic
//   C) load chosen code rows row-contiguous (8 waves x 8 tokens)
//   D) write qe coalesced
// ---------------------------------------------------------------------------
__global__ __launch_bounds__(512) void finalize_kernel(const float* __restrict__ x,
                                                       const float* __restrict__ cb,
                                                       const unsigned* __restrict__ pk1,
                                                       const unsigned* __restrict__ pk2,
                                                       float* __restrict__ qe,
                                                       float* __restrict__ idx_f,
                                                       float* __restrict__ loss) {
    __shared__ float  xt[256 * 65];     // [c][tok] transposed tile, 65-pad; reused for e rows
    __shared__ int    cnd[3][64], bsx[64];
    __shared__ double dp[3][8][64];     // [cand][cq][tok]

    const int t = threadIdx.x;
    const int n0 = blockIdx.x * 64;
    const int b = n0 >> 10, hw0 = n0 & 1023;
    const int tok_l = t & 63, cg = t >> 6;      // cg in [0,8)

    // Phase A: top-3 of the 8 per-quarter packed candidates (t<64)
    if (t < 64) {
        unsigned s1 = 0u, s2 = 0u, s3 = 0u;
        int i1 = 0x7ffffff, i2 = 0x7ffffff, i3 = 0x7ffffff;
        const int n = n0 + t;
        #pragma unroll
        for (int q = 0; q < 4; ++q) {
            const unsigned ka = pk1[q * NN + n];
            const unsigned kb = pk2[q * NN + n];
            const int ga = q * 2048 + 2047 - (int)(ka & 2047u);
            const int gb = q * 2048 + 2047 - (int)(kb & 2047u);
            top3k_insert(s1, i1, s2, i2, s3, i3, ka, ga);
            top3k_insert(s1, i1, s2, i2, s3, i3, kb, gb);
        }
        cnd[0][t] = i1; cnd[1][t] = i2; cnd[2][t] = i3;
    }

    // Phase B: stage x transposed, fully coalesced (lane = hw); 32 ch/group
    const float* xb = x + ((size_t)b << 18) + hw0 + tok_l;
    #pragma unroll 8
    for (int i = 0; i < 32; ++i) {
        const int c = cg * 32 + i;
        xt[c * 65 + tok_l] = xb[(size_t)c << 10];
    }
    __syncthreads();

    // Phase R: fp64 rescore of the 3 candidates; 8 threads per token
    {
        const int tok = t & 63, cq = t >> 6;
        const float* c0 = cb + (size_t)cnd[0][tok] * CCH + cq * 32;
        const float* c1 = cb + (size_t)cnd[1][tok] * CCH + cq * 32;
        const float* c2 = cb + (size_t)cnd[2][tok] * CCH + cq * 32;
        double d0 = 0.0, d1 = 0.0, d2 = 0.0;
        #pragma unroll
        for (int j = 0; j < 32; j += 4) {
            const f32x4 e0 = *(const f32x4*)(c0 + j);
            const f32x4 e1 = *(const f32x4*)(c1 + j);
            const f32x4 e2 = *(const f32x4*)(c2 + j);
            #pragma unroll
            for (int u = 0; u < 4; ++u) {
                const float xv = xt[(cq * 32 + j + u) * 65 + tok];
                const double dx0 = (double)xv - (double)e0[u];
                const double dx1 = (double)xv - (double)e1[u];
                const double dx2 = (double)xv - (double)e2[u];
                d0 += dx0 * dx0;
                d1 += dx1 * dx1;
                d2 += dx2 * dx2;
            }
        }
        dp[0][cq][tok] = d0; dp[1][cq][tok] = d1; dp[2][cq][tok] = d2;
    }
    __syncthreads();

    // Phase P: pick true min of the 3 per token (t<64), idx, loss atomic
    if (t < 64) {
        double dd[3]; int ii[3];
        #pragma unroll
        for (int c = 0; c < 3; ++c) {
            double s = 0.0;
            #pragma unroll
            for (int q = 0; q < 8; ++q) s += dp[c][q][t];
            dd[c] = s;
            ii[c] = cnd[c][t];
        }
        int bi = ii[0]; double bd = dd[0];
        if (dd[1] < bd || (dd[1] == bd && ii[1] < bi)) { bd = dd[1]; bi = ii[1]; }
        if (dd[2] < bd || (dd[2] == bd && ii[2] < bi)) { bd = dd[2]; bi = ii[2]; }
        bsx[t] = bi;
        idx_f[n0 + t] = (float)bi;
        float lsum = (float)bd;
        #pragma unroll
        for (int off = 32; off; off >>= 1) lsum += __shfl_down(lsum, off);
        if (t == 0) atomicAdd(loss, lsum * (1.0f / ((float)NN * (float)CCH)));
    }
    __syncthreads();

    // Phase C: load chosen code rows (row-contiguous, coalesced) into xt
    {
        const int w = t >> 6, lane = t & 63;     // 8 waves x 8 tokens
        #pragma unroll
        for (int i = 0; i < 8; ++i) {
            const int tok = w * 8 + i;
            const float* e = cb + (size_t)bsx[tok] * CCH;
            #pragma unroll
            for (int u = 0; u < 4; ++u) {
                const int c = u * 64 + lane;
                xt[c * 65 + tok] = e[c];
            }
        }
    }
    __syncthreads();

    // Phase D: write qe coalesced from the transposed LDS (lane = hw)
    float* qb = qe + ((size_t)b << 18) + hw0 + tok_l;
    #pragma unroll 8
    for (int i = 0; i < 32; ++i) {
        const int c = cg * 32 + i;
        qb[(size_t)c << 10] = xt[c * 65 + tok_l];
    }
}

// ---------------------------------------------------------------------------
extern "C" void kernel_launch(void* const* d_in, const int* in_sizes, int n_in,
                              void* d_out, int out_size, void* d_ws, size_t ws_size,
                              hipStream_t stream) {
    const float* x  = (const float*)d_in[0];
    const float* cb = (const float*)d_in[1];
    float* out = (float*)d_out;
    char* ws = (char*)d_ws;

    // A (frag-major bf16) lives in d_out's qe region; finalize rewrites qe.
    unsigned short* A  = (unsigned short*)out;
    unsigned short* B2 = (unsigned short*)(ws + B2_OFF);
    float* hn  = (float*)(ws + HN_OFF);
    unsigned* pk1 = (unsigned*)(ws + PK1_OFF);
    unsigned* pk2 = (unsigned*)(ws + PK2_OFF);

    prep_kernel    <<<256 + KK / 8, 256, 0, stream>>>(x, cb, A, B2, hn,
                                                      out + LOSS_OFF);
    vq_gemm_kernel <<<512, 256, 0, stream>>>(A, B2, hn, pk1, pk2);
    finalize_kernel<<<NN / 64, 512, 0, stream>>>(x, cb, pk1, pk2,
                                                 out, out + IDX_OFF,
                                                 out + LOSS_OFF);
}